// Round 4
// baseline (280.995 us; speedup 1.0000x reference)
//
#include <hip/hip_runtime.h>
#include <math.h>

#define B_ 4
#define S_ 2048
#define D_ 512
#define H_ 8
#define DK_ 64
#define MROWS (B_ * S_)   // 8192

typedef short bf16x8 __attribute__((ext_vector_type(8)));
typedef short bf16x4 __attribute__((ext_vector_type(4)));
typedef float f32x4 __attribute__((ext_vector_type(4)));
typedef float f32x16 __attribute__((ext_vector_type(16)));

// fp32 -> bf16 RNE (proven rounds 3-11)
static __device__ __forceinline__ unsigned short f2bf(float x) {
    unsigned int u = __float_as_uint(x);
    return (unsigned short)((u + 0x7FFFu + ((u >> 16) & 1u)) >> 16);
}
// packed fp32x2 -> bf16x2; operand->half mapping probed at runtime (r9-proven)
static __device__ __forceinline__ unsigned int cvt_pk_bf16(float a, float b) {
    unsigned int r;
    asm("v_cvt_pk_bf16_f32 %0, %1, %2" : "=v"(r) : "v"(a), "v"(b));
    return r;
}
static __device__ __forceinline__ float exp2_fast(float x) {
    float r;
    asm("v_exp_f32 %0, %1" : "=v"(r) : "v"(x));
    return r;
}
// async global->LDS DMA, 16B per lane; LDS dest is wave-uniform base + lane*16
static __device__ __forceinline__ void gld_lds16(const unsigned short* g, unsigned short* l) {
    __builtin_amdgcn_global_load_lds(
        (const __attribute__((address_space(1))) unsigned int*)g,
        (__attribute__((address_space(3))) unsigned int*)l, 16, 0, 0);
}
// v_permlane32_swap_b32: swaps a's upper 32 lanes with b's lower 32 lanes.
// Inline asm unconditionally (T12/m214-proven instr; avoids builtin-signature
// compile risk that may have killed the round-3 build).
static __device__ __forceinline__ void plswap(unsigned int& a, unsigned int& b) {
    asm volatile("v_permlane32_swap_b32 %0, %1" : "+v"(a), "+v"(b));
}

#define NXE (MROWS * D_)        // 4194304 elems
#define NWE (D_ * D_)           // 262144 elems
#define CAST_BLOCKS ((3 * NXE + 2 * NWE) / 8 / 256)   // 6400
#define MASK_BLOCKS (B_ * S_ * S_ / 256)              // 65536

// ---------------------------------------------------------------------------
// prep: fused input cast (Q,K,V,Wq,Wo -> bf16) + mask bit-pack. (r9-verbatim)
// ---------------------------------------------------------------------------
__global__ __launch_bounds__(256) void prep(const float* __restrict__ Q,
                                            const float* __restrict__ K,
                                            const float* __restrict__ V,
                                            const float* __restrict__ Wq,
                                            const float* __restrict__ Wo,
                                            const void* __restrict__ mask,
                                            unsigned short* __restrict__ Qb,
                                            unsigned short* __restrict__ Kb,
                                            unsigned short* __restrict__ Vb,
                                            unsigned short* __restrict__ Wqb,
                                            unsigned short* __restrict__ Wob,
                                            unsigned long long* __restrict__ mb) {
    if (blockIdx.x < CAST_BLOCKS) {
        const int NA = NXE / 8;
        const int NWn = NWE / 8;
        int id = blockIdx.x * 256 + threadIdx.x;
        const float* src;
        unsigned short* dst;
        if (id < 3 * NA) {
            int a = id / NA, r = id - a * NA;
            src = (a == 0 ? Q : a == 1 ? K : V) + (size_t)r * 8;
            dst = (a == 0 ? Qb : a == 1 ? Kb : Vb) + (size_t)r * 8;
        } else {
            int r = id - 3 * NA;
            int a = r / NWn; r -= a * NWn;
            src = (a == 0 ? Wq : Wo) + (size_t)r * 8;
            dst = (a == 0 ? Wqb : Wob) + (size_t)r * 8;
        }
        float4 x = *(const float4*)src;
        float4 y = *(const float4*)(src + 4);
        unsigned short u[8] = {f2bf(x.x), f2bf(x.y), f2bf(x.z), f2bf(x.w),
                               f2bf(y.x), f2bf(y.y), f2bf(y.z), f2bf(y.w)};
        *(uint4*)dst = *(const uint4*)u;
    } else {
        const int id = (blockIdx.x - CAST_BLOCKS) * 256 + threadIdx.x;
        unsigned int accw = 0;
        if ((threadIdx.x & 63) == 0) {
            const unsigned int* mw0 = (const unsigned int*)mask;
            #pragma unroll
            for (int i = 0; i < 16; ++i) accw |= mw0[i];
        }
        accw = __shfl(accw, 0);
        const bool bytemode = (accw & 0xFFFFFF00u) != 0u;
        int val;
        if (bytemode) val = ((const unsigned char*)mask)[id];
        else          val = ((const int*)mask)[id];
        unsigned long long w = __ballot(val != 0);
        if ((threadIdx.x & 63) == 0) mb[id >> 6] = w;
    }
}

// ---------------------------------------------------------------------------
// QKV projection (r9-verbatim). z=0: qs = proj * 0.125*log2e; z=1: k; z=2: V^T.
// ---------------------------------------------------------------------------
__global__ __launch_bounds__(256) void proj3(const unsigned short* __restrict__ Qb,
                                             const unsigned short* __restrict__ Kb,
                                             const unsigned short* __restrict__ Vb,
                                             const unsigned short* __restrict__ Wqb,
                                             unsigned short* __restrict__ qs,
                                             unsigned short* __restrict__ kbo,
                                             unsigned short* __restrict__ vt) {
    __shared__ unsigned short As[128 * 40];
    __shared__ unsigned short Bs[128 * 40];
    const int t = threadIdx.x;
    const int w = t >> 6, lane = t & 63, col = lane & 15, quad = lane >> 4;
    const int bm = blockIdx.x * 128, bn = blockIdx.y * 128;
    const int z = blockIdx.z;
    const unsigned short* X = (z == 0) ? Qb : (z == 1) ? Kb : Vb;
    const int wm = (w >> 1) * 64, wn = (w & 1) * 64;
    const int srow = t >> 1, shalf = t & 1;

    const unsigned short* xg = X + (size_t)(bm + srow) * D_ + shalf * 16;
    const unsigned short* wg = Wqb + (size_t)(bn + srow) * D_ + shalf * 16;
    unsigned short* asw = &As[srow * 40 + shalf * 16];
    unsigned short* bsw = &Bs[srow * 40 + shalf * 16];

    f32x4 acc[4][4];
    #pragma unroll
    for (int i = 0; i < 4; ++i)
        #pragma unroll
        for (int j = 0; j < 4; ++j) acc[i][j] = (f32x4){0.f, 0.f, 0.f, 0.f};

    #pragma unroll 1
    for (int k0 = 0; k0 < D_; k0 += 32) {
        __syncthreads();
        {
            uint4 a0 = *(const uint4*)(xg + k0);
            uint4 a1 = *(const uint4*)(xg + k0 + 8);
            uint4 b0 = *(const uint4*)(wg + k0);
            uint4 b1 = *(const uint4*)(wg + k0 + 8);
            *(uint4*)asw = a0; *(uint4*)(asw + 8) = a1;
            *(uint4*)bsw = b0; *(uint4*)(bsw + 8) = b1;
        }
        __syncthreads();

        bf16x8 af[4], bg[4];
        #pragma unroll
        for (int i = 0; i < 4; ++i)
            af[i] = *(const bf16x8*)&As[(wm + i * 16 + col) * 40 + quad * 8];
        #pragma unroll
        for (int j = 0; j < 4; ++j)
            bg[j] = *(const bf16x8*)&Bs[(wn + j * 16 + col) * 40 + quad * 8];
        #pragma unroll
        for (int i = 0; i < 4; ++i)
            #pragma unroll
            for (int j = 0; j < 4; ++j)
                acc[i][j] = __builtin_amdgcn_mfma_f32_16x16x32_bf16(
                    af[i], bg[j], acc[i][j], 0, 0, 0);
    }

    if (z == 2) {
        #pragma unroll
        for (int i = 0; i < 4; ++i) {
            const int R = bm + wm + i * 16 + quad * 4;
            const int bb = R >> 11, s0 = R & (S_ - 1);
            #pragma unroll
            for (int j = 0; j < 4; ++j) {
                const int C = bn + wn + j * 16 + col;
                const int hh = C >> 6, dd = C & (DK_ - 1);
                ushort4 u = make_ushort4(f2bf(acc[i][j][0]), f2bf(acc[i][j][1]),
                                         f2bf(acc[i][j][2]), f2bf(acc[i][j][3]));
                *(ushort4*)&vt[(((size_t)bb * H_ + hh) * DK_ + dd) * S_ + s0] = u;
            }
        }
    } else {
        unsigned short* O = (z == 0) ? qs : kbo;
        const float scl = (z == 0) ? 0.18033688f : 1.0f;  // 0.125 * log2(e)
        #pragma unroll
        for (int i = 0; i < 4; ++i)
            #pragma unroll
            for (int j = 0; j < 4; ++j) {
                const int R = bm + wm + i * 16 + quad * 4;
                const int C = bn + wn + j * 16 + col;
                #pragma unroll
                for (int r = 0; r < 4; ++r)
                    O[(size_t)(R + r) * D_ + C] = f2bf(acc[i][j][r] * scl);
            }
    }
}

// ---------------------------------------------------------------------------
// Output GEMM (r9-verbatim).
// ---------------------------------------------------------------------------
__global__ __launch_bounds__(256) void gemm_out(const unsigned short* __restrict__ Xb,
                                                const unsigned short* __restrict__ Wob,
                                                float* __restrict__ Out) {
    __shared__ unsigned short As[128 * 40];
    __shared__ unsigned short Bs[128 * 40];
    const int t = threadIdx.x;
    const int w = t >> 6, lane = t & 63, col = lane & 15, quad = lane >> 4;
    const int bm = blockIdx.x * 128, bn = blockIdx.y * 128;
    const int wm = (w >> 1) * 64, wn = (w & 1) * 64;
    const int srow = t >> 1, shalf = t & 1;

    const unsigned short* xg = Xb + (size_t)(bm + srow) * D_ + shalf * 16;
    const unsigned short* wg = Wob + (size_t)(bn + srow) * D_ + shalf * 16;
    unsigned short* asw = &As[srow * 40 + shalf * 16];
    unsigned short* bsw = &Bs[srow * 40 + shalf * 16];

    f32x4 acc[4][4];
    #pragma unroll
    for (int i = 0; i < 4; ++i)
        #pragma unroll
        for (int j = 0; j < 4; ++j) acc[i][j] = (f32x4){0.f, 0.f, 0.f, 0.f};

    #pragma unroll 1
    for (int k0 = 0; k0 < D_; k0 += 32) {
        __syncthreads();
        {
            uint4 a0 = *(const uint4*)(xg + k0);
            uint4 a1 = *(const uint4*)(xg + k0 + 8);
            uint4 b0 = *(const uint4*)(wg + k0);
            uint4 b1 = *(const uint4*)(wg + k0 + 8);
            *(uint4*)asw = a0; *(uint4*)(asw + 8) = a1;
            *(uint4*)bsw = b0; *(uint4*)(bsw + 8) = b1;
        }
        __syncthreads();

        bf16x8 af[4], bg[4];
        #pragma unroll
        for (int i = 0; i < 4; ++i)
            af[i] = *(const bf16x8*)&As[(wm + i * 16 + col) * 40 + quad * 8];
        #pragma unroll
        for (int j = 0; j < 4; ++j)
            bg[j] = *(const bf16x8*)&Bs[(wn + j * 16 + col) * 40 + quad * 8];
        #pragma unroll
        for (int i = 0; i < 4; ++i)
            #pragma unroll
            for (int j = 0; j < 4; ++j)
                acc[i][j] = __builtin_amdgcn_mfma_f32_16x16x32_bf16(
                    af[i], bg[j], acc[i][j], 0, 0, 0);
    }

    #pragma unroll
    for (int i = 0; i < 4; ++i)
        #pragma unroll
        for (int j = 0; j < 4; ++j) {
            const int R = bm + wm + i * 16 + quad * 4;
            const int C = bn + wn + j * 16 + col;
            #pragma unroll
            for (int r = 0; r < 4; ++r)
                Out[(size_t)(R + r) * D_ + C] = acc[i][j][r];
        }
}

// ---------------------------------------------------------------------------
// MFMA flash attention v6b (= v6 resubmit; round-3 failure was infra/build —
// permlane builtin replaced by inline asm, everything else identical).
// All-32x32x16 pipeline (full-rate opcode; v5's 16x16x16 PV ran at legacy
// quarter rate -> matrix pipe was the limiter). Wave = 32 q-rows. Swapped
// QK^T: S^T = mfma(A=K, B=Q) chained over 4 dk slices -> lane holds
// S^T[k=(r&3)+8*(r>>2)+4*hi][q=lane&31]. mask/exp in-register (1 mask u64
// per lane per tile), then cvt_pk pairs + v_permlane32_swap_b32 (2 per
// 16k-slice) put P into the 32x32x16 A-fragment layout (lane row=q,
// k=hi*8+j) with ZERO LDS traffic. PV: O[dblk] += mfma(pa, Vt-frag);
// l-rowsum: mfma(pa, ones). 20 mfma32/tile ~160 cyc. K/V DMA staging,
// double-buffer, source-XOR swizzle, counted vmcnt, raw s_barriers:
// v5-verbatim. LDS 32KB, 4 blocks/CU.
// ---------------------------------------------------------------------------
__global__ __launch_bounds__(256, 4) void attn_mfma(
        const unsigned short* __restrict__ qb,
        const unsigned short* __restrict__ kb,
        const unsigned short* __restrict__ vt,
        const unsigned long long* __restrict__ mb,
        unsigned short* __restrict__ o0,
        unsigned short* __restrict__ o1,
        float* __restrict__ l0,
        float* __restrict__ l1) {
    // [K buf0 4096][V buf0 4096][K buf1 4096][V buf1 4096]  (shorts)
    __shared__ unsigned short sm[16384];
    const int t = threadIdx.x;            // 0..255
    const int w = t >> 6;                 // wave 0..3
    const int lane = t & 63;
    const int q5 = lane & 31;             // q-row within wave / col index
    const int hi = lane >> 5;             // lane half
    const int h = blockIdx.y;
    const int b = blockIdx.z >> 1;
    const int khalf = blockIdx.z & 1;
    const int bh = b * H_ + h;
    const int qrow0 = blockIdx.x * 128 + w * 32;  // this wave's first q-row

    unsigned short* opart = khalf ? o1 : o0;
    float* lpart = khalf ? l1 : l0;

    // runtime probe: operand->half order of v_cvt_pk_bf16_f32 (r9-proven)
    const unsigned int chk = cvt_pk_bf16(1.0f, 2.0f);
    const bool ablow = ((chk & 0xFFFFu) == 0x3F80u);

    // Q B-fragments: qf[dsl] = Q[qrow0+q5][dsl*16 + hi*8 .. +8] (pre-scaled)
    bf16x8 qf[4];
    {
        const unsigned short* qp =
            qb + (size_t)(b * S_ + qrow0 + q5) * D_ + h * DK_ + hi * 8;
        #pragma unroll
        for (int dsl = 0; dsl < 4; ++dsl)
            qf[dsl] = *(const bf16x8*)(qp + dsl * 16);
    }

    bf16x8 ones8;
    #pragma unroll
    for (int i = 0; i < 8; ++i) ones8[i] = (short)0x3F80;  // bf16 1.0

    f32x16 Oa, Ob, lacc;
    #pragma unroll
    for (int i = 0; i < 16; ++i) { Oa[i] = 0.f; Ob[i] = 0.f; lacc[i] = 0.f; }

    const float CREF = 8.656170245f;  // 6 * log2(e)
    const int kbeg = khalf * (S_ / 2);

    // ---- DMA staging: per-lane XOR-swizzled global source (v4/v5-proven) ---
    const int ln8 = lane >> 3;
    const int fs8 = ((lane & 7) ^ ln8) * 8;       // fetch seg offset (shorts)
    const int r0 = w * 16 + ln8;                  // j=0 row (k-idx / dk-idx)
    const unsigned short* pK0 = kb + (size_t)(b * S_ + kbeg + r0) * D_ + h * DK_ + fs8;
    const unsigned short* pK1 = pK0 + 8 * D_;     // j=1: +8 rows
    const unsigned short* pV0 = vt + ((size_t)bh * DK_ + r0) * S_ + kbeg + fs8;
    const unsigned short* pV1 = pV0 + 8 * S_;

    // mask words: one u64 per lane per tile, row = qrow0 + q5
    const unsigned long long* mbase =
        mb + (size_t)(b * S_ + qrow0 + q5) * (S_ / 64) + (kbeg >> 6);

    // ---- prologue: stage tile 0 -> buf0 ------------------------------------
    gld_lds16(pK0, &sm[w * 1024]);
    gld_lds16(pK1, &sm[w * 1024 + 512]);
    gld_lds16(pV0, &sm[4096 + w * 1024]);
    gld_lds16(pV1, &sm[4096 + w * 1024 + 512]);
    pK0 += 64 * D_; pK1 += 64 * D_; pV0 += 64; pV1 += 64;

    const int x7 = (q5 & 7);                      // row-XOR for fragment reads

    #pragma unroll 1
    for (int ti = 0; ti < 16; ++ti) {
        // mask for THIS tile, issued BEFORE the DMA prefetch (vmcnt order)
        unsigned long long mw = mbase[ti];
        __builtin_amdgcn_sched_barrier(0);
        if (ti < 15) {
            const int nb = (ti & 1) ? 0 : 8192;   // prefetch target buffer
            gld_lds16(pK0, &sm[nb + w * 1024]);
            gld_lds16(pK1, &sm[nb + w * 1024 + 512]);
            gld_lds16(pV0, &sm[nb + 4096 + w * 1024]);
            gld_lds16(pV1, &sm[nb + 4096 + w * 1024 + 512]);
            pK0 += 64 * D_; pK1 += 64 * D_; pV0 += 64; pV1 += 64;
            // outstanding: DMA(ti)x4 (oldest) + mask + DMA(ti+1)x4 -> complete
            // the 4 oldest; mask is auto-waited by the compiler at first use
            __asm__ __volatile__("s_waitcnt vmcnt(5)" ::: "memory");
        } else {
            __asm__ __volatile__("s_waitcnt vmcnt(1)" ::: "memory");
        }
        __builtin_amdgcn_s_barrier();

        const int KB = (ti & 1) ? 8192 : 0;
        const int VB = KB + 4096;
        const unsigned long long msh = mw >> (hi * 4);

        #pragma unroll
        for (int kbi = 0; kbi < 2; ++kbi) {
            // S^T = mfma(A=K-frag, B=Q-frag), chained over 4 dk-slices
            const int krow = KB + (kbi * 32 + q5) * 64;
            f32x16 S;
            #pragma unroll
            for (int i = 0; i < 16; ++i) S[i] = 0.f;
            __builtin_amdgcn_s_setprio(1);
            #pragma unroll
            for (int dsl = 0; dsl < 4; ++dsl) {
                bf16x8 kf = *(const bf16x8*)&sm[krow + (((dsl << 1) | hi) ^ x7) * 8];
                S = __builtin_amdgcn_mfma_f32_32x32x16_bf16(kf, qf[dsl], S, 0, 0, 0);
            }
            __builtin_amdgcn_s_setprio(0);

            // mask -> p = 2^(s' - CREF), all in-register
            float p[16];
            #pragma unroll
            for (int r = 0; r < 16; ++r) {
                const int c = kbi * 32 + (r & 3) + 8 * (r >> 2);
                const bool msk = ((msh >> c) & 1ull) != 0ull;
                p[r] = exp2_fast((msk ? -1e30f : S[r]) - CREF);
            }

            // pack + permlane32_swap -> 32x32x16 A-fragments; l + PV mfma
            #pragma unroll
            for (int ksl = 0; ksl < 2; ++ksl) {
                const int bsl = ksl * 8;
                unsigned int uA = ablow ? cvt_pk_bf16(p[bsl], p[bsl + 1])
                                        : cvt_pk_bf16(p[bsl + 1], p[bsl]);
                unsigned int uB = ablow ? cvt_pk_bf16(p[bsl + 2], p[bsl + 3])
                                        : cvt_pk_bf16(p[bsl + 3], p[bsl + 2]);
                unsigned int uC = ablow ? cvt_pk_bf16(p[bsl + 4], p[bsl + 5])
                                        : cvt_pk_bf16(p[bsl + 5], p[bsl + 4]);
                unsigned int uD = ablow ? cvt_pk_bf16(p[bsl + 6], p[bsl + 7])
                                        : cvt_pk_bf16(p[bsl + 7], p[bsl + 6]);
                plswap(uA, uC);   // -> u[0] (all lanes), u[2] (all lanes)
                plswap(uB, uD);   // -> u[1], u[3]
                union { unsigned int u[4]; bf16x8 v; } pa;
                pa.u[0] = uA; pa.u[1] = uB; pa.u[2] = uC; pa.u[3] = uD;

                const int slice = kbi * 2 + ksl;
                const int vseg = (((slice << 1) | hi) ^ x7) * 8;
                bf16x8 vf0 = *(const bf16x8*)&sm[VB + q5 * 64 + vseg];
                bf16x8 vf1 = *(const bf16x8*)&sm[VB + (32 + q5) * 64 + vseg];
                __builtin_amdgcn_s_setprio(1);
                lacc = __builtin_amdgcn_mfma_f32_32x32x16_bf16(pa.v, ones8, lacc, 0, 0, 0);
                Oa = __builtin_amdgcn_mfma_f32_32x32x16_bf16(pa.v, vf0, Oa, 0, 0, 0);
                Ob = __builtin_amdgcn_mfma_f32_32x32x16_bf16(pa.v, vf1, Ob, 0, 0, 0);
                __builtin_amdgcn_s_setprio(0);
            }
        }

        // all waves done reading this buffer before next iter's DMA overwrites
        __builtin_amdgcn_s_barrier();
    }

    // epilogue: store UNNORMALIZED O (bf16) + l (fp32) partials
    #pragma unroll
    for (int r = 0; r < 16; ++r) {
        const int qq = (r & 3) + 8 * (r >> 2) + 4 * hi;
        const size_t row = (size_t)(b * S_ + qrow0 + qq);
        opart[row * D_ + h * DK_ + q5]      = f2bf(Oa[r]);
        opart[row * D_ + h * DK_ + 32 + q5] = f2bf(Ob[r]);
        if (q5 == 0) lpart[row * H_ + h] = lacc[r];
    }
}

// ---------------------------------------------------------------------------
// combine: cbuf = (O0 + O1) / (l0 + l1), bf16 out. 8 elems/thread.
// ---------------------------------------------------------------------------
__global__ __launch_bounds__(256) void combine(const unsigned short* __restrict__ o0,
                                               const unsigned short* __restrict__ o1,
                                               const float* __restrict__ l0,
                                               const float* __restrict__ l1,
                                               unsigned short* __restrict__ cb) {
    const int id = blockIdx.x * 256 + threadIdx.x;   // 0 .. NXE/8-1
    const size_t base = (size_t)id * 8;
    const int row = (int)(base >> 9);                // /D_
    const int hh = ((int)base & (D_ - 1)) >> 6;
    uint4 ua = *(const uint4*)(o0 + base);
    uint4 ub = *(const uint4*)(o1 + base);
    const float inv = 1.0f / (l0[(size_t)row * H_ + hh] + l1[(size_t)row * H_ + hh]);
    const unsigned short* pa = (const unsigned short*)&ua;
    const unsigned short* pb = (const unsigned short*)&ub;
    unsigned short out[8];
    #pragma unroll
    for (int i = 0; i < 8; ++i) {
        float fa = __uint_as_float((unsigned int)pa[i] << 16);
        float fb = __uint_as_float((unsigned int)pb[i] << 16);
        out[i] = f2bf((fa + fb) * inv);
    }
    *(uint4*)(cb + base) = *(const uint4*)out;
}

// ---------------------------------------------------------------------------
extern "C" void kernel_launch(void* const* d_in, const int* in_sizes, int n_in,
                              void* d_out, int out_size, void* d_ws, size_t ws_size,
                              hipStream_t stream) {
    const float* Q    = (const float*)d_in[0];
    const float* K    = (const float*)d_in[1];
    const float* V    = (const float*)d_in[2];
    const void*  mask = d_in[3];
    const float* Wq   = (const float*)d_in[4];
    const float* Wo   = (const float*)d_in[5];
    float* out = (float*)d_out;

    // workspace carve (~62 MB). After proj3, Qb/Kb/Vb are dead -> overlay the
    // attention partial buffers on them (stream-ordered, re-written each call).
    const size_t NX = (size_t)MROWS * D_;
    const size_t NW = (size_t)D_ * D_;
    unsigned short* Qb   = (unsigned short*)d_ws;   // bf16 input casts
    unsigned short* Kb   = Qb + NX;
    unsigned short* Vb   = Kb + NX;
    unsigned short* Wqb  = Vb + NX;
    unsigned short* Wob  = Wqb + NW;
    unsigned short* qbuf = Wob + NW;                // q proj * 0.125*log2e (bf16)
    unsigned short* kbuf = qbuf + NX;               // k proj (bf16 RM)
    unsigned short* vtb  = kbuf + NX;               // V^T (bf16)
    unsigned short* cbuf = vtb + NX;                // context (bf16 RM)
    unsigned long long* mb = (unsigned long long*)(cbuf + NX);

    unsigned short* o0 = Qb;                        // overlay: partial O half 0
    unsigned short* o1 = Kb;                        // overlay: partial O half 1
    float* l0 = (float*)Vb;                         // overlay: partial l half 0
    float* l1 = l0 + (size_t)MROWS * H_;            // partial l half 1

    prep<<<dim3(CAST_BLOCKS + MASK_BLOCKS), dim3(256), 0, stream>>>(
        Q, K, V, Wq, Wo, mask, Qb, Kb, Vb, Wqb, Wob, mb);

    proj3<<<dim3(MROWS / 128, D_ / 128, 3), dim3(256), 0, stream>>>(
        Qb, Kb, Vb, Wqb, qbuf, kbuf, vtb);

    attn_mfma<<<dim3(S_ / 128, H_, B_ * 2), dim3(256), 0, stream>>>(
        qbuf, kbuf, vtb, mb, o0, o1, l0, l1);

    combine<<<dim3((int)(NX / 8 / 256)), dim3(256), 0, stream>>>(o0, o1, l0, l1, cbuf);

    gemm_out<<<dim3(MROWS / 128, D_ / 128), dim3(256), 0, stream>>>(cbuf, Wob, out);
}

// Round 5
// 266.388 us; speedup vs baseline: 1.0548x; 1.0548x over previous
//
#include <hip/hip_runtime.h>
#include <math.h>

#define B_ 4
#define S_ 2048
#define D_ 512
#define H_ 8
#define DK_ 64
#define MROWS (B_ * S_)   // 8192

typedef short bf16x8 __attribute__((ext_vector_type(8)));
typedef float f32x4 __attribute__((ext_vector_type(4)));
typedef float f32x16 __attribute__((ext_vector_type(16)));

// fp32 -> bf16 RNE (proven rounds 3-11)
static __device__ __forceinline__ unsigned short f2bf(float x) {
    unsigned int u = __float_as_uint(x);
    return (unsigned short)((u + 0x7FFFu + ((u >> 16) & 1u)) >> 16);
}
// packed fp32x2 -> bf16x2; operand->half mapping probed at runtime (r9-proven)
static __device__ __forceinline__ unsigned int cvt_pk_bf16(float a, float b) {
    unsigned int r;
    asm("v_cvt_pk_bf16_f32 %0, %1, %2" : "=v"(r) : "v"(a), "v"(b));
    return r;
}
static __device__ __forceinline__ float exp2_fast(float x) {
    float r;
    asm("v_exp_f32 %0, %1" : "=v"(r) : "v"(x));
    return r;
}
// async global->LDS DMA, 16B per lane; LDS dest is wave-uniform base + lane*16
static __device__ __forceinline__ void gld_lds16(const unsigned short* g, unsigned short* l) {
    __builtin_amdgcn_global_load_lds(
        (const __attribute__((address_space(1))) unsigned int*)g,
        (__attribute__((address_space(3))) unsigned int*)l, 16, 0, 0);
}
// v_permlane32_swap_b32: swaps a's upper 32 lanes with b's lower 32 lanes.
static __device__ __forceinline__ void plswap(unsigned int& a, unsigned int& b) {
    asm volatile("v_permlane32_swap_b32 %0, %1" : "+v"(a), "+v"(b));
}

#define NXE (MROWS * D_)        // 4194304 elems
#define NWE (D_ * D_)           // 262144 elems
#define CAST_BLOCKS ((3 * NXE + 2 * NWE) / 8 / 256)   // 6400
#define MASK_BLOCKS (B_ * S_ * S_ / 256)              // 65536

// ---------------------------------------------------------------------------
// prep: fused input cast (Q,K,V,Wq,Wo -> bf16) + mask bit-pack. (r9-verbatim)
// ---------------------------------------------------------------------------
__global__ __launch_bounds__(256) void prep(const float* __restrict__ Q,
                                            const float* __restrict__ K,
                                            const float* __restrict__ V,
                                            const float* __restrict__ Wq,
                                            const float* __restrict__ Wo,
                                            const void* __restrict__ mask,
                                            unsigned short* __restrict__ Qb,
                                            unsigned short* __restrict__ Kb,
                                            unsigned short* __restrict__ Vb,
                                            unsigned short* __restrict__ Wqb,
                                            unsigned short* __restrict__ Wob,
                                            unsigned long long* __restrict__ mb) {
    if (blockIdx.x < CAST_BLOCKS) {
        const int NA = NXE / 8;
        const int NWn = NWE / 8;
        int id = blockIdx.x * 256 + threadIdx.x;
        const float* src;
        unsigned short* dst;
        if (id < 3 * NA) {
            int a = id / NA, r = id - a * NA;
            src = (a == 0 ? Q : a == 1 ? K : V) + (size_t)r * 8;
            dst = (a == 0 ? Qb : a == 1 ? Kb : Vb) + (size_t)r * 8;
        } else {
            int r = id - 3 * NA;
            int a = r / NWn; r -= a * NWn;
            src = (a == 0 ? Wq : Wo) + (size_t)r * 8;
            dst = (a == 0 ? Wqb : Wob) + (size_t)r * 8;
        }
        float4 x = *(const float4*)src;
        float4 y = *(const float4*)(src + 4);
        unsigned short u[8] = {f2bf(x.x), f2bf(x.y), f2bf(x.z), f2bf(x.w),
                               f2bf(y.x), f2bf(y.y), f2bf(y.z), f2bf(y.w)};
        *(uint4*)dst = *(const uint4*)u;
    } else {
        const int id = (blockIdx.x - CAST_BLOCKS) * 256 + threadIdx.x;
        unsigned int accw = 0;
        if ((threadIdx.x & 63) == 0) {
            const unsigned int* mw0 = (const unsigned int*)mask;
            #pragma unroll
            for (int i = 0; i < 16; ++i) accw |= mw0[i];
        }
        accw = __shfl(accw, 0);
        const bool bytemode = (accw & 0xFFFFFF00u) != 0u;
        int val;
        if (bytemode) val = ((const unsigned char*)mask)[id];
        else          val = ((const int*)mask)[id];
        unsigned long long w = __ballot(val != 0);
        if ((threadIdx.x & 63) == 0) mb[id >> 6] = w;
    }
}

// ---------------------------------------------------------------------------
// QKV projection v2: same fragments/MFMA/epilogue as r9, but staging is now
// global_load_lds(16B) DMA into double-buffered LINEAR [128][32] LDS with
// XOR-swizzled SOURCE addressing: data at (row r, phys seg s) comes from
// global seg s ^ ((r>>1)&3); fragment reads use pseg = quad ^ ((col>>1)&3).
// Bank-slot check: b128 reads hit 8 distinct 16B slots over cols 0-7, 2-way
// over 16 lanes = free (same as the old +8-short pad). One vmcnt(0)+barrier
// per k-step (T3-minimum 2-phase); next tile's DMAs issue before compute.
// ---------------------------------------------------------------------------
__global__ __launch_bounds__(256) void proj3(const unsigned short* __restrict__ Qb,
                                             const unsigned short* __restrict__ Kb,
                                             const unsigned short* __restrict__ Vb,
                                             const unsigned short* __restrict__ Wqb,
                                             unsigned short* __restrict__ qs,
                                             unsigned short* __restrict__ kbo,
                                             unsigned short* __restrict__ vt) {
    // [As0 4096][Bs0 4096][As1 4096][Bs1 4096] shorts = 32 KB
    __shared__ unsigned short smx[16384];
    const int t = threadIdx.x;
    const int w = t >> 6, lane = t & 63, col = lane & 15, quad = lane >> 4;
    const int bm = blockIdx.x * 128, bn = blockIdx.y * 128;
    const int z = blockIdx.z;
    const unsigned short* X = (z == 0) ? Qb : (z == 1) ? Kb : Vb;
    const int wm = (w >> 1) * 64, wn = (w & 1) * 64;

    // staging: unit u=(w*2+j)*64+lane -> row r=w*32+j*16+(lane>>2), seg s=lane&3
    // source seg = s ^ ((r>>1)&3) = (lane&3) ^ ((lane>>3)&3)
    const int sr = w * 32 + (lane >> 2);
    const int ssw = (((lane & 3) ^ ((lane >> 3) & 3)) * 8);
    const unsigned short* ags = X + (size_t)(bm + sr) * D_ + ssw;
    const unsigned short* bgs = Wqb + (size_t)(bn + sr) * D_ + ssw;
    const int pseg = ((quad ^ ((col >> 1) & 3)) * 8);  // fragment-read swizzle

    f32x4 acc[4][4];
    #pragma unroll
    for (int i = 0; i < 4; ++i)
        #pragma unroll
        for (int j = 0; j < 4; ++j) acc[i][j] = (f32x4){0.f, 0.f, 0.f, 0.f};

    // prologue: stage k0=0 -> buf0
    gld_lds16(ags, &smx[w * 1024]);
    gld_lds16(ags + 16 * D_, &smx[w * 1024 + 512]);
    gld_lds16(bgs, &smx[4096 + w * 1024]);
    gld_lds16(bgs + 16 * D_, &smx[4096 + w * 1024 + 512]);
    __asm__ __volatile__("s_waitcnt vmcnt(0)" ::: "memory");
    __builtin_amdgcn_s_barrier();

    int cur = 0;
    #pragma unroll 1
    for (int k0 = 0; k0 < D_; k0 += 32) {
        if (k0 + 32 < D_) {
            const int nb = (cur ^ 1) * 8192;
            gld_lds16(ags + k0 + 32, &smx[nb + w * 1024]);
            gld_lds16(ags + 16 * D_ + k0 + 32, &smx[nb + w * 1024 + 512]);
            gld_lds16(bgs + k0 + 32, &smx[nb + 4096 + w * 1024]);
            gld_lds16(bgs + 16 * D_ + k0 + 32, &smx[nb + 4096 + w * 1024 + 512]);
        }
        __builtin_amdgcn_sched_barrier(0);

        const int cb = cur * 8192;
        bf16x8 af[4], bg[4];
        #pragma unroll
        for (int i = 0; i < 4; ++i)
            af[i] = *(const bf16x8*)&smx[cb + (wm + i * 16 + col) * 32 + pseg];
        #pragma unroll
        for (int j = 0; j < 4; ++j)
            bg[j] = *(const bf16x8*)&smx[cb + 4096 + (wn + j * 16 + col) * 32 + pseg];
        #pragma unroll
        for (int i = 0; i < 4; ++i)
            #pragma unroll
            for (int j = 0; j < 4; ++j)
                acc[i][j] = __builtin_amdgcn_mfma_f32_16x16x32_bf16(
                    af[i], bg[j], acc[i][j], 0, 0, 0);

        __asm__ __volatile__("s_waitcnt vmcnt(0)" ::: "memory");
        __builtin_amdgcn_s_barrier();
        cur ^= 1;
    }

    if (z == 2) {
        #pragma unroll
        for (int i = 0; i < 4; ++i) {
            const int R = bm + wm + i * 16 + quad * 4;
            const int bb = R >> 11, s0 = R & (S_ - 1);
            #pragma unroll
            for (int j = 0; j < 4; ++j) {
                const int C = bn + wn + j * 16 + col;
                const int hh = C >> 6, dd = C & (DK_ - 1);
                ushort4 u = make_ushort4(f2bf(acc[i][j][0]), f2bf(acc[i][j][1]),
                                         f2bf(acc[i][j][2]), f2bf(acc[i][j][3]));
                *(ushort4*)&vt[(((size_t)bb * H_ + hh) * DK_ + dd) * S_ + s0] = u;
            }
        }
    } else {
        unsigned short* O = (z == 0) ? qs : kbo;
        const float scl = (z == 0) ? 0.18033688f : 1.0f;  // 0.125 * log2(e)
        #pragma unroll
        for (int i = 0; i < 4; ++i)
            #pragma unroll
            for (int j = 0; j < 4; ++j) {
                const int R = bm + wm + i * 16 + quad * 4;
                const int C = bn + wn + j * 16 + col;
                #pragma unroll
                for (int r = 0; r < 4; ++r)
                    O[(size_t)(R + r) * D_ + C] = f2bf(acc[i][j][r] * scl);
            }
    }
}

// ---------------------------------------------------------------------------
// Output GEMM v2: same gload_lds double-buffered staging as proj3 v2.
// ---------------------------------------------------------------------------
__global__ __launch_bounds__(256) void gemm_out(const unsigned short* __restrict__ Xb,
                                                const unsigned short* __restrict__ Wob,
                                                float* __restrict__ Out) {
    __shared__ unsigned short smx[16384];
    const int t = threadIdx.x;
    const int w = t >> 6, lane = t & 63, col = lane & 15, quad = lane >> 4;
    const int bm = blockIdx.x * 128, bn = blockIdx.y * 128;
    const int wm = (w >> 1) * 64, wn = (w & 1) * 64;

    const int sr = w * 32 + (lane >> 2);
    const int ssw = (((lane & 3) ^ ((lane >> 3) & 3)) * 8);
    const unsigned short* ags = Xb + (size_t)(bm + sr) * D_ + ssw;
    const unsigned short* bgs = Wob + (size_t)(bn + sr) * D_ + ssw;
    const int pseg = ((quad ^ ((col >> 1) & 3)) * 8);

    f32x4 acc[4][4];
    #pragma unroll
    for (int i = 0; i < 4; ++i)
        #pragma unroll
        for (int j = 0; j < 4; ++j) acc[i][j] = (f32x4){0.f, 0.f, 0.f, 0.f};

    gld_lds16(ags, &smx[w * 1024]);
    gld_lds16(ags + 16 * D_, &smx[w * 1024 + 512]);
    gld_lds16(bgs, &smx[4096 + w * 1024]);
    gld_lds16(bgs + 16 * D_, &smx[4096 + w * 1024 + 512]);
    __asm__ __volatile__("s_waitcnt vmcnt(0)" ::: "memory");
    __builtin_amdgcn_s_barrier();

    int cur = 0;
    #pragma unroll 1
    for (int k0 = 0; k0 < D_; k0 += 32) {
        if (k0 + 32 < D_) {
            const int nb = (cur ^ 1) * 8192;
            gld_lds16(ags + k0 + 32, &smx[nb + w * 1024]);
            gld_lds16(ags + 16 * D_ + k0 + 32, &smx[nb + w * 1024 + 512]);
            gld_lds16(bgs + k0 + 32, &smx[nb + 4096 + w * 1024]);
            gld_lds16(bgs + 16 * D_ + k0 + 32, &smx[nb + 4096 + w * 1024 + 512]);
        }
        __builtin_amdgcn_sched_barrier(0);

        const int cb = cur * 8192;
        bf16x8 af[4], bg[4];
        #pragma unroll
        for (int i = 0; i < 4; ++i)
            af[i] = *(const bf16x8*)&smx[cb + (wm + i * 16 + col) * 32 + pseg];
        #pragma unroll
        for (int j = 0; j < 4; ++j)
            bg[j] = *(const bf16x8*)&smx[cb + 4096 + (wn + j * 16 + col) * 32 + pseg];
        #pragma unroll
        for (int i = 0; i < 4; ++i)
            #pragma unroll
            for (int j = 0; j < 4; ++j)
                acc[i][j] = __builtin_amdgcn_mfma_f32_16x16x32_bf16(
                    af[i], bg[j], acc[i][j], 0, 0, 0);

        __asm__ __volatile__("s_waitcnt vmcnt(0)" ::: "memory");
        __builtin_amdgcn_s_barrier();
        cur ^= 1;
    }

    #pragma unroll
    for (int i = 0; i < 4; ++i)
        #pragma unroll
        for (int j = 0; j < 4; ++j) {
            const int R = bm + wm + i * 16 + quad * 4;
            const int C = bn + wn + j * 16 + col;
            #pragma unroll
            for (int r = 0; r < 4; ++r)
                Out[(size_t)(R + r) * D_ + C] = acc[i][j][r];
        }
}

// ---------------------------------------------------------------------------
// MFMA flash attention v6b (round-4 passing version, byte-identical).
// ---------------------------------------------------------------------------
__global__ __launch_bounds__(256, 4) void attn_mfma(
        const unsigned short* __restrict__ qb,
        const unsigned short* __restrict__ kb,
        const unsigned short* __restrict__ vt,
        const unsigned long long* __restrict__ mb,
        unsigned short* __restrict__ o0,
        unsigned short* __restrict__ o1,
        float* __restrict__ l0,
        float* __restrict__ l1) {
    // [K buf0 4096][V buf0 4096][K buf1 4096][V buf1 4096]  (shorts)
    __shared__ unsigned short sm[16384];
    const int t = threadIdx.x;            // 0..255
    const int w = t >> 6;                 // wave 0..3
    const int lane = t & 63;
    const int q5 = lane & 31;             // q-row within wave / col index
    const int hi = lane >> 5;             // lane half
    const int h = blockIdx.y;
    const int b = blockIdx.z >> 1;
    const int khalf = blockIdx.z & 1;
    const int bh = b * H_ + h;
    const int qrow0 = blockIdx.x * 128 + w * 32;  // this wave's first q-row

    unsigned short* opart = khalf ? o1 : o0;
    float* lpart = khalf ? l1 : l0;

    // runtime probe: operand->half order of v_cvt_pk_bf16_f32 (r9-proven)
    const unsigned int chk = cvt_pk_bf16(1.0f, 2.0f);
    const bool ablow = ((chk & 0xFFFFu) == 0x3F80u);

    // Q B-fragments: qf[dsl] = Q[qrow0+q5][dsl*16 + hi*8 .. +8] (pre-scaled)
    bf16x8 qf[4];
    {
        const unsigned short* qp =
            qb + (size_t)(b * S_ + qrow0 + q5) * D_ + h * DK_ + hi * 8;
        #pragma unroll
        for (int dsl = 0; dsl < 4; ++dsl)
            qf[dsl] = *(const bf16x8*)(qp + dsl * 16);
    }

    bf16x8 ones8;
    #pragma unroll
    for (int i = 0; i < 8; ++i) ones8[i] = (short)0x3F80;  // bf16 1.0

    f32x16 Oa, Ob, lacc;
    #pragma unroll
    for (int i = 0; i < 16; ++i) { Oa[i] = 0.f; Ob[i] = 0.f; lacc[i] = 0.f; }

    const float CREF = 8.656170245f;  // 6 * log2(e)
    const int kbeg = khalf * (S_ / 2);

    // ---- DMA staging: per-lane XOR-swizzled global source (v4/v5-proven) ---
    const int ln8 = lane >> 3;
    const int fs8 = ((lane & 7) ^ ln8) * 8;       // fetch seg offset (shorts)
    const int r0 = w * 16 + ln8;                  // j=0 row (k-idx / dk-idx)
    const unsigned short* pK0 = kb + (size_t)(b * S_ + kbeg + r0) * D_ + h * DK_ + fs8;
    const unsigned short* pK1 = pK0 + 8 * D_;     // j=1: +8 rows
    const unsigned short* pV0 = vt + ((size_t)bh * DK_ + r0) * S_ + kbeg + fs8;
    const unsigned short* pV1 = pV0 + 8 * S_;

    // mask words: one u64 per lane per tile, row = qrow0 + q5
    const unsigned long long* mbase =
        mb + (size_t)(b * S_ + qrow0 + q5) * (S_ / 64) + (kbeg >> 6);

    // ---- prologue: stage tile 0 -> buf0 ------------------------------------
    gld_lds16(pK0, &sm[w * 1024]);
    gld_lds16(pK1, &sm[w * 1024 + 512]);
    gld_lds16(pV0, &sm[4096 + w * 1024]);
    gld_lds16(pV1, &sm[4096 + w * 1024 + 512]);
    pK0 += 64 * D_; pK1 += 64 * D_; pV0 += 64; pV1 += 64;

    const int x7 = (q5 & 7);                      // row-XOR for fragment reads

    #pragma unroll 1
    for (int ti = 0; ti < 16; ++ti) {
        // mask for THIS tile, issued BEFORE the DMA prefetch (vmcnt order)
        unsigned long long mw = mbase[ti];
        __builtin_amdgcn_sched_barrier(0);
        if (ti < 15) {
            const int nb = (ti & 1) ? 0 : 8192;   // prefetch target buffer
            gld_lds16(pK0, &sm[nb + w * 1024]);
            gld_lds16(pK1, &sm[nb + w * 1024 + 512]);
            gld_lds16(pV0, &sm[nb + 4096 + w * 1024]);
            gld_lds16(pV1, &sm[nb + 4096 + w * 1024 + 512]);
            pK0 += 64 * D_; pK1 += 64 * D_; pV0 += 64; pV1 += 64;
            // outstanding: DMA(ti)x4 (oldest) + mask + DMA(ti+1)x4 -> complete
            // the 4 oldest; mask is auto-waited by the compiler at first use
            __asm__ __volatile__("s_waitcnt vmcnt(5)" ::: "memory");
        } else {
            __asm__ __volatile__("s_waitcnt vmcnt(1)" ::: "memory");
        }
        __builtin_amdgcn_s_barrier();

        const int KB = (ti & 1) ? 8192 : 0;
        const int VB = KB + 4096;
        const unsigned long long msh = mw >> (hi * 4);

        #pragma unroll
        for (int kbi = 0; kbi < 2; ++kbi) {
            // S^T = mfma(A=K-frag, B=Q-frag), chained over 4 dk-slices
            const int krow = KB + (kbi * 32 + q5) * 64;
            f32x16 S;
            #pragma unroll
            for (int i = 0; i < 16; ++i) S[i] = 0.f;
            __builtin_amdgcn_s_setprio(1);
            #pragma unroll
            for (int dsl = 0; dsl < 4; ++dsl) {
                bf16x8 kf = *(const bf16x8*)&sm[krow + (((dsl << 1) | hi) ^ x7) * 8];
                S = __builtin_amdgcn_mfma_f32_32x32x16_bf16(kf, qf[dsl], S, 0, 0, 0);
            }
            __builtin_amdgcn_s_setprio(0);

            // mask -> p = 2^(s' - CREF), all in-register
            float p[16];
            #pragma unroll
            for (int r = 0; r < 16; ++r) {
                const int c = kbi * 32 + (r & 3) + 8 * (r >> 2);
                const bool msk = ((msh >> c) & 1ull) != 0ull;
                p[r] = exp2_fast((msk ? -1e30f : S[r]) - CREF);
            }

            // pack + permlane32_swap -> 32x32x16 A-fragments; l + PV mfma
            #pragma unroll
            for (int ksl = 0; ksl < 2; ++ksl) {
                const int bsl = ksl * 8;
                unsigned int uA = ablow ? cvt_pk_bf16(p[bsl], p[bsl + 1])
                                        : cvt_pk_bf16(p[bsl + 1], p[bsl]);
                unsigned int uB = ablow ? cvt_pk_bf16(p[bsl + 2], p[bsl + 3])
                                        : cvt_pk_bf16(p[bsl + 3], p[bsl + 2]);
                unsigned int uC = ablow ? cvt_pk_bf16(p[bsl + 4], p[bsl + 5])
                                        : cvt_pk_bf16(p[bsl + 5], p[bsl + 4]);
                unsigned int uD = ablow ? cvt_pk_bf16(p[bsl + 6], p[bsl + 7])
                                        : cvt_pk_bf16(p[bsl + 7], p[bsl + 6]);
                plswap(uA, uC);   // -> u[0] (all lanes), u[2] (all lanes)
                plswap(uB, uD);   // -> u[1], u[3]
                union { unsigned int u[4]; bf16x8 v; } pa;
                pa.u[0] = uA; pa.u[1] = uB; pa.u[2] = uC; pa.u[3] = uD;

                const int slice = kbi * 2 + ksl;
                const int vseg = (((slice << 1) | hi) ^ x7) * 8;
                bf16x8 vf0 = *(const bf16x8*)&sm[VB + q5 * 64 + vseg];
                bf16x8 vf1 = *(const bf16x8*)&sm[VB + (32 + q5) * 64 + vseg];
                __builtin_amdgcn_s_setprio(1);
                lacc = __builtin_amdgcn_mfma_f32_32x32x16_bf16(pa.v, ones8, lacc, 0, 0, 0);
                Oa = __builtin_amdgcn_mfma_f32_32x32x16_bf16(pa.v, vf0, Oa, 0, 0, 0);
                Ob = __builtin_amdgcn_mfma_f32_32x32x16_bf16(pa.v, vf1, Ob, 0, 0, 0);
                __builtin_amdgcn_s_setprio(0);
            }
        }

        // all waves done reading this buffer before next iter's DMA overwrites
        __builtin_amdgcn_s_barrier();
    }

    // epilogue: store UNNORMALIZED O (bf16) + l (fp32) partials
    #pragma unroll
    for (int r = 0; r < 16; ++r) {
        const int qq = (r & 3) + 8 * (r >> 2) + 4 * hi;
        const size_t row = (size_t)(b * S_ + qrow0 + qq);
        opart[row * D_ + h * DK_ + q5]      = f2bf(Oa[r]);
        opart[row * D_ + h * DK_ + 32 + q5] = f2bf(Ob[r]);
        if (q5 == 0) lpart[row * H_ + h] = lacc[r];
    }
}

// ---------------------------------------------------------------------------
// combine: cbuf = (O0 + O1) / (l0 + l1), bf16 out. 8 elems/thread.
// ---------------------------------------------------------------------------
__global__ __launch_bounds__(256) void combine(const unsigned short* __restrict__ o0,
                                               const unsigned short* __restrict__ o1,
                                               const float* __restrict__ l0,
                                               const float* __restrict__ l1,
                                               unsigned short* __restrict__ cb) {
    const int id = blockIdx.x * 256 + threadIdx.x;   // 0 .. NXE/8-1
    const size_t base = (size_t)id * 8;
    const int row = (int)(base >> 9);                // /D_
    const int hh = ((int)base & (D_ - 1)) >> 6;
    uint4 ua = *(const uint4*)(o0 + base);
    uint4 ub = *(const uint4*)(o1 + base);
    const float inv = 1.0f / (l0[(size_t)row * H_ + hh] + l1[(size_t)row * H_ + hh]);
    const unsigned short* pa = (const unsigned short*)&ua;
    const unsigned short* pb = (const unsigned short*)&ub;
    unsigned short out[8];
    #pragma unroll
    for (int i = 0; i < 8; ++i) {
        float fa = __uint_as_float((unsigned int)pa[i] << 16);
        float fb = __uint_as_float((unsigned int)pb[i] << 16);
        out[i] = f2bf((fa + fb) * inv);
    }
    *(uint4*)(cb + base) = *(const uint4*)out;
}

// ---------------------------------------------------------------------------
extern "C" void kernel_launch(void* const* d_in, const int* in_sizes, int n_in,
                              void* d_out, int out_size, void* d_ws, size_t ws_size,
                              hipStream_t stream) {
    const float* Q    = (const float*)d_in[0];
    const float* K    = (const float*)d_in[1];
    const float* V    = (const float*)d_in[2];
    const void*  mask = d_in[3];
    const float* Wq   = (const float*)d_in[4];
    const float* Wo   = (const float*)d_in[5];
    float* out = (float*)d_out;

    // workspace carve (~62 MB). After proj3, Qb/Kb/Vb are dead -> overlay the
    // attention partial buffers on them (stream-ordered, re-written each call).
    const size_t NX = (size_t)MROWS * D_;
    const size_t NW = (size_t)D_ * D_;
    unsigned short* Qb   = (unsigned short*)d_ws;   // bf16 input casts
    unsigned short* Kb   = Qb + NX;
    unsigned short* Vb   = Kb + NX;
    unsigned short* Wqb  = Vb + NX;
    unsigned short* Wob  = Wqb + NW;
    unsigned short* qbuf = Wob + NW;                // q proj * 0.125*log2e (bf16)
    unsigned short* kbuf = qbuf + NX;               // k proj (bf16 RM)
    unsigned short* vtb  = kbuf + NX;               // V^T (bf16)
    unsigned short* cbuf = vtb + NX;                // context (bf16 RM)
    unsigned long long* mb = (unsigned long long*)(cbuf + NX);

    unsigned short* o0 = Qb;                        // overlay: partial O half 0
    unsigned short* o1 = Kb;                        // overlay: partial O half 1
    float* l0 = (float*)Vb;                         // overlay: partial l half 0
    float* l1 = l0 + (size_t)MROWS * H_;            // partial l half 1

    prep<<<dim3(CAST_BLOCKS + MASK_BLOCKS), dim3(256), 0, stream>>>(
        Q, K, V, Wq, Wo, mask, Qb, Kb, Vb, Wqb, Wob, mb);

    proj3<<<dim3(MROWS / 128, D_ / 128, 3), dim3(256), 0, stream>>>(
        Qb, Kb, Vb, Wqb, qbuf, kbuf, vtb);

    attn_mfma<<<dim3(S_ / 128, H_, B_ * 2), dim3(256), 0, stream>>>(
        qbuf, kbuf, vtb, mb, o0, o1, l0, l1);

    combine<<<dim3((int)(NX / 8 / 256)), dim3(256), 0, stream>>>(o0, o1, l0, l1, cbuf);

    gemm_out<<<dim3(MROWS / 128, D_ / 128), dim3(256), 0, stream>>>(cbuf, Wob, out);
}

// Round 6
// 245.386 us; speedup vs baseline: 1.1451x; 1.0856x over previous
//
#include <hip/hip_runtime.h>
#include <math.h>

#define B_ 4
#define S_ 2048
#define D_ 512
#define H_ 8
#define DK_ 64
#define MROWS (B_ * S_)   // 8192

typedef short bf16x8 __attribute__((ext_vector_type(8)));
typedef float f32x4 __attribute__((ext_vector_type(4)));
typedef float f32x16 __attribute__((ext_vector_type(16)));

// fp32 -> bf16 RNE (proven rounds 3-11)
static __device__ __forceinline__ unsigned short f2bf(float x) {
    unsigned int u = __float_as_uint(x);
    return (unsigned short)((u + 0x7FFFu + ((u >> 16) & 1u)) >> 16);
}
// packed fp32x2 -> bf16x2; operand->half mapping probed at runtime (r9-proven)
static __device__ __forceinline__ unsigned int cvt_pk_bf16(float a, float b) {
    unsigned int r;
    asm("v_cvt_pk_bf16_f32 %0, %1, %2" : "=v"(r) : "v"(a), "v"(b));
    return r;
}
static __device__ __forceinline__ float exp2_fast(float x) {
    float r;
    asm("v_exp_f32 %0, %1" : "=v"(r) : "v"(x));
    return r;
}
// async global->LDS DMA, 16B per lane; LDS dest is wave-uniform base + lane*16
static __device__ __forceinline__ void gld_lds16(const unsigned short* g, unsigned short* l) {
    __builtin_amdgcn_global_load_lds(
        (const __attribute__((address_space(1))) unsigned int*)g,
        (__attribute__((address_space(3))) unsigned int*)l, 16, 0, 0);
}
// v_permlane32_swap_b32: swaps a's upper 32 lanes with b's lower 32 lanes.
static __device__ __forceinline__ void plswap(unsigned int& a, unsigned int& b) {
    asm volatile("v_permlane32_swap_b32 %0, %1" : "+v"(a), "+v"(b));
}

#define NXE (MROWS * D_)        // 4194304 elems
#define NWE (D_ * D_)           // 262144 elems
#define CAST_BLOCKS ((3 * NXE + 2 * NWE) / 8 / 256)   // 6400
#define MASKE (B_ * S_ * S_)                          // 16777216 mask elems
#define MASK_BLOCKS (MASKE / 256 / 4)                 // 16384 (int mode: 4/thread)
#define MASKB_BYTE (MASKE / 256 / 16)                 // 4096 (byte mode: 16/thread)

// ---------------------------------------------------------------------------
// prep v2: fused input cast (unchanged) + VECTORIZED mask bit-pack.
// Byte mode: 16 B/thread -> OR-cascade per u32 + carry-free mul bit-gather
// ((y*0x01020408)>>24 = b0|b1<<1|b2<<2|b3<<3), store one u16 piece (LE u16
// overlay == u64 bit layout). Int mode: 4 stride-64 words/thread + 4 ballots.
// Old path was 1 B/thread x 65536 blocks = instruction-bound (~35 us).
// ---------------------------------------------------------------------------
__global__ __launch_bounds__(256) void prep(const float* __restrict__ Q,
                                            const float* __restrict__ K,
                                            const float* __restrict__ V,
                                            const float* __restrict__ Wq,
                                            const float* __restrict__ Wo,
                                            const void* __restrict__ mask,
                                            unsigned short* __restrict__ Qb,
                                            unsigned short* __restrict__ Kb,
                                            unsigned short* __restrict__ Vb,
                                            unsigned short* __restrict__ Wqb,
                                            unsigned short* __restrict__ Wob,
                                            unsigned long long* __restrict__ mb) {
    if (blockIdx.x < CAST_BLOCKS) {
        const int NA = NXE / 8;
        const int NWn = NWE / 8;
        int id = blockIdx.x * 256 + threadIdx.x;
        const float* src;
        unsigned short* dst;
        if (id < 3 * NA) {
            int a = id / NA, r = id - a * NA;
            src = (a == 0 ? Q : a == 1 ? K : V) + (size_t)r * 8;
            dst = (a == 0 ? Qb : a == 1 ? Kb : Vb) + (size_t)r * 8;
        } else {
            int r = id - 3 * NA;
            int a = r / NWn; r -= a * NWn;
            src = (a == 0 ? Wq : Wo) + (size_t)r * 8;
            dst = (a == 0 ? Wqb : Wob) + (size_t)r * 8;
        }
        float4 x = *(const float4*)src;
        float4 y = *(const float4*)(src + 4);
        unsigned short u[8] = {f2bf(x.x), f2bf(x.y), f2bf(x.z), f2bf(x.w),
                               f2bf(y.x), f2bf(y.y), f2bf(y.z), f2bf(y.w)};
        *(uint4*)dst = *(const uint4*)u;
    } else {
        const int mblk = blockIdx.x - CAST_BLOCKS;
        // dtype probe (r9-proven): first 16 words; byte mask sets upper bytes
        unsigned int accw = 0;
        if ((threadIdx.x & 63) == 0) {
            const unsigned int* mw0 = (const unsigned int*)mask;
            #pragma unroll
            for (int i = 0; i < 16; ++i) accw |= mw0[i];
        }
        accw = __shfl(accw, 0);
        const bool bytemode = (accw & 0xFFFFFF00u) != 0u;
        if (bytemode) {
            if (mblk >= MASKB_BYTE) return;
            const int gid = mblk * 256 + threadIdx.x;   // u16-piece index
            uint4 x = ((const uint4*)mask)[gid];
            unsigned int n[4];
            const unsigned int xs[4] = {x.x, x.y, x.z, x.w};
            #pragma unroll
            for (int i = 0; i < 4; ++i) {
                unsigned int y = xs[i];
                y |= y >> 4; y |= y >> 2; y |= y >> 1;
                y &= 0x01010101u;
                n[i] = (y * 0x01020408u) >> 24;   // b0|b1<<1|b2<<2|b3<<3
            }
            const unsigned short piece =
                (unsigned short)(n[0] | (n[1] << 4) | (n[2] << 8) | (n[3] << 12));
            ((unsigned short*)mb)[gid] = piece;
        } else {
            // int32 mask: wave handles 256 consecutive elems via 4 ballots
            const int wid = (mblk * 256 + threadIdx.x) >> 6;
            const int lane = threadIdx.x & 63;
            const unsigned int* mi = (const unsigned int*)mask;
            const size_t base = (size_t)wid * 256;
            unsigned long long b0 = __ballot(mi[base + lane] != 0);
            unsigned long long b1 = __ballot(mi[base + 64 + lane] != 0);
            unsigned long long b2 = __ballot(mi[base + 128 + lane] != 0);
            unsigned long long b3 = __ballot(mi[base + 192 + lane] != 0);
            if (lane == 0) {
                const size_t wix = base >> 6;
                mb[wix] = b0; mb[wix + 1] = b1; mb[wix + 2] = b2; mb[wix + 3] = b3;
            }
        }
    }
}

// ---------------------------------------------------------------------------
// QKV projection v2 (r5-verbatim, passing): gload_lds(16B) double-buffered
// staging with source-XOR swizzle; one vmcnt(0)+barrier per k-step.
// ---------------------------------------------------------------------------
__global__ __launch_bounds__(256) void proj3(const unsigned short* __restrict__ Qb,
                                             const unsigned short* __restrict__ Kb,
                                             const unsigned short* __restrict__ Vb,
                                             const unsigned short* __restrict__ Wqb,
                                             unsigned short* __restrict__ qs,
                                             unsigned short* __restrict__ kbo,
                                             unsigned short* __restrict__ vt) {
    __shared__ unsigned short smx[16384];
    const int t = threadIdx.x;
    const int w = t >> 6, lane = t & 63, col = lane & 15, quad = lane >> 4;
    const int bm = blockIdx.x * 128, bn = blockIdx.y * 128;
    const int z = blockIdx.z;
    const unsigned short* X = (z == 0) ? Qb : (z == 1) ? Kb : Vb;
    const int wm = (w >> 1) * 64, wn = (w & 1) * 64;

    const int sr = w * 32 + (lane >> 2);
    const int ssw = (((lane & 3) ^ ((lane >> 3) & 3)) * 8);
    const unsigned short* ags = X + (size_t)(bm + sr) * D_ + ssw;
    const unsigned short* bgs = Wqb + (size_t)(bn + sr) * D_ + ssw;
    const int pseg = ((quad ^ ((col >> 1) & 3)) * 8);

    f32x4 acc[4][4];
    #pragma unroll
    for (int i = 0; i < 4; ++i)
        #pragma unroll
        for (int j = 0; j < 4; ++j) acc[i][j] = (f32x4){0.f, 0.f, 0.f, 0.f};

    gld_lds16(ags, &smx[w * 1024]);
    gld_lds16(ags + 16 * D_, &smx[w * 1024 + 512]);
    gld_lds16(bgs, &smx[4096 + w * 1024]);
    gld_lds16(bgs + 16 * D_, &smx[4096 + w * 1024 + 512]);
    __asm__ __volatile__("s_waitcnt vmcnt(0)" ::: "memory");
    __builtin_amdgcn_s_barrier();

    int cur = 0;
    #pragma unroll 1
    for (int k0 = 0; k0 < D_; k0 += 32) {
        if (k0 + 32 < D_) {
            const int nb = (cur ^ 1) * 8192;
            gld_lds16(ags + k0 + 32, &smx[nb + w * 1024]);
            gld_lds16(ags + 16 * D_ + k0 + 32, &smx[nb + w * 1024 + 512]);
            gld_lds16(bgs + k0 + 32, &smx[nb + 4096 + w * 1024]);
            gld_lds16(bgs + 16 * D_ + k0 + 32, &smx[nb + 4096 + w * 1024 + 512]);
        }
        __builtin_amdgcn_sched_barrier(0);

        const int cb = cur * 8192;
        bf16x8 af[4], bg[4];
        #pragma unroll
        for (int i = 0; i < 4; ++i)
            af[i] = *(const bf16x8*)&smx[cb + (wm + i * 16 + col) * 32 + pseg];
        #pragma unroll
        for (int j = 0; j < 4; ++j)
            bg[j] = *(const bf16x8*)&smx[cb + 4096 + (wn + j * 16 + col) * 32 + pseg];
        #pragma unroll
        for (int i = 0; i < 4; ++i)
            #pragma unroll
            for (int j = 0; j < 4; ++j)
                acc[i][j] = __builtin_amdgcn_mfma_f32_16x16x32_bf16(
                    af[i], bg[j], acc[i][j], 0, 0, 0);

        __asm__ __volatile__("s_waitcnt vmcnt(0)" ::: "memory");
        __builtin_amdgcn_s_barrier();
        cur ^= 1;
    }

    if (z == 2) {
        #pragma unroll
        for (int i = 0; i < 4; ++i) {
            const int R = bm + wm + i * 16 + quad * 4;
            const int bb = R >> 11, s0 = R & (S_ - 1);
            #pragma unroll
            for (int j = 0; j < 4; ++j) {
                const int C = bn + wn + j * 16 + col;
                const int hh = C >> 6, dd = C & (DK_ - 1);
                ushort4 u = make_ushort4(f2bf(acc[i][j][0]), f2bf(acc[i][j][1]),
                                         f2bf(acc[i][j][2]), f2bf(acc[i][j][3]));
                *(ushort4*)&vt[(((size_t)bb * H_ + hh) * DK_ + dd) * S_ + s0] = u;
            }
        }
    } else {
        unsigned short* O = (z == 0) ? qs : kbo;
        const float scl = (z == 0) ? 0.18033688f : 1.0f;  // 0.125 * log2(e)
        #pragma unroll
        for (int i = 0; i < 4; ++i)
            #pragma unroll
            for (int j = 0; j < 4; ++j) {
                const int R = bm + wm + i * 16 + quad * 4;
                const int C = bn + wn + j * 16 + col;
                #pragma unroll
                for (int r = 0; r < 4; ++r)
                    O[(size_t)(R + r) * D_ + C] = f2bf(acc[i][j][r] * scl);
            }
    }
}

// ---------------------------------------------------------------------------
// Output GEMM v2 (r5-verbatim, passing).
// ---------------------------------------------------------------------------
__global__ __launch_bounds__(256) void gemm_out(const unsigned short* __restrict__ Xb,
                                                const unsigned short* __restrict__ Wob,
                                                float* __restrict__ Out) {
    __shared__ unsigned short smx[16384];
    const int t = threadIdx.x;
    const int w = t >> 6, lane = t & 63, col = lane & 15, quad = lane >> 4;
    const int bm = blockIdx.x * 128, bn = blockIdx.y * 128;
    const int wm = (w >> 1) * 64, wn = (w & 1) * 64;

    const int sr = w * 32 + (lane >> 2);
    const int ssw = (((lane & 3) ^ ((lane >> 3) & 3)) * 8);
    const unsigned short* ags = Xb + (size_t)(bm + sr) * D_ + ssw;
    const unsigned short* bgs = Wob + (size_t)(bn + sr) * D_ + ssw;
    const int pseg = ((quad ^ ((col >> 1) & 3)) * 8);

    f32x4 acc[4][4];
    #pragma unroll
    for (int i = 0; i < 4; ++i)
        #pragma unroll
        for (int j = 0; j < 4; ++j) acc[i][j] = (f32x4){0.f, 0.f, 0.f, 0.f};

    gld_lds16(ags, &smx[w * 1024]);
    gld_lds16(ags + 16 * D_, &smx[w * 1024 + 512]);
    gld_lds16(bgs, &smx[4096 + w * 1024]);
    gld_lds16(bgs + 16 * D_, &smx[4096 + w * 1024 + 512]);
    __asm__ __volatile__("s_waitcnt vmcnt(0)" ::: "memory");
    __builtin_amdgcn_s_barrier();

    int cur = 0;
    #pragma unroll 1
    for (int k0 = 0; k0 < D_; k0 += 32) {
        if (k0 + 32 < D_) {
            const int nb = (cur ^ 1) * 8192;
            gld_lds16(ags + k0 + 32, &smx[nb + w * 1024]);
            gld_lds16(ags + 16 * D_ + k0 + 32, &smx[nb + w * 1024 + 512]);
            gld_lds16(bgs + k0 + 32, &smx[nb + 4096 + w * 1024]);
            gld_lds16(bgs + 16 * D_ + k0 + 32, &smx[nb + 4096 + w * 1024 + 512]);
        }
        __builtin_amdgcn_sched_barrier(0);

        const int cb = cur * 8192;
        bf16x8 af[4], bg[4];
        #pragma unroll
        for (int i = 0; i < 4; ++i)
            af[i] = *(const bf16x8*)&smx[cb + (wm + i * 16 + col) * 32 + pseg];
        #pragma unroll
        for (int j = 0; j < 4; ++j)
            bg[j] = *(const bf16x8*)&smx[cb + 4096 + (wn + j * 16 + col) * 32 + pseg];
        #pragma unroll
        for (int i = 0; i < 4; ++i)
            #pragma unroll
            for (int j = 0; j < 4; ++j)
                acc[i][j] = __builtin_amdgcn_mfma_f32_16x16x32_bf16(
                    af[i], bg[j], acc[i][j], 0, 0, 0);

        __asm__ __volatile__("s_waitcnt vmcnt(0)" ::: "memory");
        __builtin_amdgcn_s_barrier();
        cur ^= 1;
    }

    #pragma unroll
    for (int i = 0; i < 4; ++i)
        #pragma unroll
        for (int j = 0; j < 4; ++j) {
            const int R = bm + wm + i * 16 + quad * 4;
            const int C = bn + wn + j * 16 + col;
            #pragma unroll
            for (int r = 0; r < 4; ++r)
                Out[(size_t)(R + r) * D_ + C] = acc[i][j][r];
        }
}

// ---------------------------------------------------------------------------
// MFMA flash attention v6c: v6b + crefv accumulator-bake. Persistent
// crefv = {-CREF}x16 feeds the first QK mfma as C-in, so S arrives with
// -CREF already applied: deletes 32 v_sub + 16 zero-init movs per wave-tile.
// Everything else byte-identical to the round-4/5 passing version.
// ---------------------------------------------------------------------------
__global__ __launch_bounds__(256, 4) void attn_mfma(
        const unsigned short* __restrict__ qb,
        const unsigned short* __restrict__ kb,
        const unsigned short* __restrict__ vt,
        const unsigned long long* __restrict__ mb,
        unsigned short* __restrict__ o0,
        unsigned short* __restrict__ o1,
        float* __restrict__ l0,
        float* __restrict__ l1) {
    // [K buf0 4096][V buf0 4096][K buf1 4096][V buf1 4096]  (shorts)
    __shared__ unsigned short sm[16384];
    const int t = threadIdx.x;            // 0..255
    const int w = t >> 6;                 // wave 0..3
    const int lane = t & 63;
    const int q5 = lane & 31;             // q-row within wave / col index
    const int hi = lane >> 5;             // lane half
    const int h = blockIdx.y;
    const int b = blockIdx.z >> 1;
    const int khalf = blockIdx.z & 1;
    const int bh = b * H_ + h;
    const int qrow0 = blockIdx.x * 128 + w * 32;  // this wave's first q-row

    unsigned short* opart = khalf ? o1 : o0;
    float* lpart = khalf ? l1 : l0;

    // runtime probe: operand->half order of v_cvt_pk_bf16_f32 (r9-proven)
    const unsigned int chk = cvt_pk_bf16(1.0f, 2.0f);
    const bool ablow = ((chk & 0xFFFFu) == 0x3F80u);

    // Q B-fragments: qf[dsl] = Q[qrow0+q5][dsl*16 + hi*8 .. +8] (pre-scaled)
    bf16x8 qf[4];
    {
        const unsigned short* qp =
            qb + (size_t)(b * S_ + qrow0 + q5) * D_ + h * DK_ + hi * 8;
        #pragma unroll
        for (int dsl = 0; dsl < 4; ++dsl)
            qf[dsl] = *(const bf16x8*)(qp + dsl * 16);
    }

    bf16x8 ones8;
    #pragma unroll
    for (int i = 0; i < 8; ++i) ones8[i] = (short)0x3F80;  // bf16 1.0

    const float CREF = 8.656170245f;  // 6 * log2(e)
    f32x16 Oa, Ob, lacc, crefv;
    #pragma unroll
    for (int i = 0; i < 16; ++i) {
        Oa[i] = 0.f; Ob[i] = 0.f; lacc[i] = 0.f; crefv[i] = -CREF;
    }

    const int kbeg = khalf * (S_ / 2);

    // ---- DMA staging: per-lane XOR-swizzled global source (v4/v5-proven) ---
    const int ln8 = lane >> 3;
    const int fs8 = ((lane & 7) ^ ln8) * 8;       // fetch seg offset (shorts)
    const int r0 = w * 16 + ln8;                  // j=0 row (k-idx / dk-idx)
    const unsigned short* pK0 = kb + (size_t)(b * S_ + kbeg + r0) * D_ + h * DK_ + fs8;
    const unsigned short* pK1 = pK0 + 8 * D_;     // j=1: +8 rows
    const unsigned short* pV0 = vt + ((size_t)bh * DK_ + r0) * S_ + kbeg + fs8;
    const unsigned short* pV1 = pV0 + 8 * S_;

    // mask words: one u64 per lane per tile, row = qrow0 + q5
    const unsigned long long* mbase =
        mb + (size_t)(b * S_ + qrow0 + q5) * (S_ / 64) + (kbeg >> 6);

    // ---- prologue: stage tile 0 -> buf0 ------------------------------------
    gld_lds16(pK0, &sm[w * 1024]);
    gld_lds16(pK1, &sm[w * 1024 + 512]);
    gld_lds16(pV0, &sm[4096 + w * 1024]);
    gld_lds16(pV1, &sm[4096 + w * 1024 + 512]);
    pK0 += 64 * D_; pK1 += 64 * D_; pV0 += 64; pV1 += 64;

    const int x7 = (q5 & 7);                      // row-XOR for fragment reads

    #pragma unroll 1
    for (int ti = 0; ti < 16; ++ti) {
        // mask for THIS tile, issued BEFORE the DMA prefetch (vmcnt order)
        unsigned long long mw = mbase[ti];
        __builtin_amdgcn_sched_barrier(0);
        if (ti < 15) {
            const int nb = (ti & 1) ? 0 : 8192;   // prefetch target buffer
            gld_lds16(pK0, &sm[nb + w * 1024]);
            gld_lds16(pK1, &sm[nb + w * 1024 + 512]);
            gld_lds16(pV0, &sm[nb + 4096 + w * 1024]);
            gld_lds16(pV1, &sm[nb + 4096 + w * 1024 + 512]);
            pK0 += 64 * D_; pK1 += 64 * D_; pV0 += 64; pV1 += 64;
            // outstanding: DMA(ti)x4 (oldest) + mask + DMA(ti+1)x4 -> complete
            // the 4 oldest; mask is auto-waited by the compiler at first use
            __asm__ __volatile__("s_waitcnt vmcnt(5)" ::: "memory");
        } else {
            __asm__ __volatile__("s_waitcnt vmcnt(1)" ::: "memory");
        }
        __builtin_amdgcn_s_barrier();

        const int KB = (ti & 1) ? 8192 : 0;
        const int VB = KB + 4096;
        const unsigned long long msh = mw >> (hi * 4);

        #pragma unroll
        for (int kbi = 0; kbi < 2; ++kbi) {
            // S^T = mfma(A=K-frag, B=Q-frag), C-in = crefv (-CREF pre-applied)
            const int krow = KB + (kbi * 32 + q5) * 64;
            __builtin_amdgcn_s_setprio(1);
            bf16x8 kf0 = *(const bf16x8*)&sm[krow + ((hi) ^ x7) * 8];
            f32x16 S = __builtin_amdgcn_mfma_f32_32x32x16_bf16(kf0, qf[0], crefv, 0, 0, 0);
            #pragma unroll
            for (int dsl = 1; dsl < 4; ++dsl) {
                bf16x8 kf = *(const bf16x8*)&sm[krow + (((dsl << 1) | hi) ^ x7) * 8];
                S = __builtin_amdgcn_mfma_f32_32x32x16_bf16(kf, qf[dsl], S, 0, 0, 0);
            }
            __builtin_amdgcn_s_setprio(0);

            // mask -> p = 2^(s' already offset by -CREF), all in-register
            float p[16];
            #pragma unroll
            for (int r = 0; r < 16; ++r) {
                const int c = kbi * 32 + (r & 3) + 8 * (r >> 2);
                const bool msk = ((msh >> c) & 1ull) != 0ull;
                p[r] = exp2_fast(msk ? -1e30f : S[r]);
            }

            // pack + permlane32_swap -> 32x32x16 A-fragments; l + PV mfma
            #pragma unroll
            for (int ksl = 0; ksl < 2; ++ksl) {
                const int bsl = ksl * 8;
                unsigned int uA = ablow ? cvt_pk_bf16(p[bsl], p[bsl + 1])
                                        : cvt_pk_bf16(p[bsl + 1], p[bsl]);
                unsigned int uB = ablow ? cvt_pk_bf16(p[bsl + 2], p[bsl + 3])
                                        : cvt_pk_bf16(p[bsl + 3], p[bsl + 2]);
                unsigned int uC = ablow ? cvt_pk_bf16(p[bsl + 4], p[bsl + 5])
                                        : cvt_pk_bf16(p[bsl + 5], p[bsl + 4]);
                unsigned int uD = ablow ? cvt_pk_bf16(p[bsl + 6], p[bsl + 7])
                                        : cvt_pk_bf16(p[bsl + 7], p[bsl + 6]);
                plswap(uA, uC);   // -> u[0] (all lanes), u[2] (all lanes)
                plswap(uB, uD);   // -> u[1], u[3]
                union { unsigned int u[4]; bf16x8 v; } pa;
                pa.u[0] = uA; pa.u[1] = uB; pa.u[2] = uC; pa.u[3] = uD;

                const int slice = kbi * 2 + ksl;
                const int vseg = (((slice << 1) | hi) ^ x7) * 8;
                bf16x8 vf0 = *(const bf16x8*)&sm[VB + q5 * 64 + vseg];
                bf16x8 vf1 = *(const bf16x8*)&sm[VB + (32 + q5) * 64 + vseg];
                __builtin_amdgcn_s_setprio(1);
                lacc = __builtin_amdgcn_mfma_f32_32x32x16_bf16(pa.v, ones8, lacc, 0, 0, 0);
                Oa = __builtin_amdgcn_mfma_f32_32x32x16_bf16(pa.v, vf0, Oa, 0, 0, 0);
                Ob = __builtin_amdgcn_mfma_f32_32x32x16_bf16(pa.v, vf1, Ob, 0, 0, 0);
                __builtin_amdgcn_s_setprio(0);
            }
        }

        // all waves done reading this buffer before next iter's DMA overwrites
        __builtin_amdgcn_s_barrier();
    }

    // epilogue: store UNNORMALIZED O (bf16) + l (fp32) partials
    #pragma unroll
    for (int r = 0; r < 16; ++r) {
        const int qq = (r & 3) + 8 * (r >> 2) + 4 * hi;
        const size_t row = (size_t)(b * S_ + qrow0 + qq);
        opart[row * D_ + h * DK_ + q5]      = f2bf(Oa[r]);
        opart[row * D_ + h * DK_ + 32 + q5] = f2bf(Ob[r]);
        if (q5 == 0) lpart[row * H_ + h] = lacc[r];
    }
}

// ---------------------------------------------------------------------------
// combine: cbuf = (O0 + O1) / (l0 + l1), bf16 out. 8 elems/thread.
// ---------------------------------------------------------------------------
__global__ __launch_bounds__(256) void combine(const unsigned short* __restrict__ o0,
                                               const unsigned short* __restrict__ o1,
                                               const float* __restrict__ l0,
                                               const float* __restrict__ l1,
                                               unsigned short* __restrict__ cb) {
    const int id = blockIdx.x * 256 + threadIdx.x;   // 0 .. NXE/8-1
    const size_t base = (size_t)id * 8;
    const int row = (int)(base >> 9);                // /D_
    const int hh = ((int)base & (D_ - 1)) >> 6;
    uint4 ua = *(const uint4*)(o0 + base);
    uint4 ub = *(const uint4*)(o1 + base);
    const float inv = 1.0f / (l0[(size_t)row * H_ + hh] + l1[(size_t)row * H_ + hh]);
    const unsigned short* pa = (const unsigned short*)&ua;
    const unsigned short* pb = (const unsigned short*)&ub;
    unsigned short out[8];
    #pragma unroll
    for (int i = 0; i < 8; ++i) {
        float fa = __uint_as_float((unsigned int)pa[i] << 16);
        float fb = __uint_as_float((unsigned int)pb[i] << 16);
        out[i] = f2bf((fa + fb) * inv);
    }
    *(uint4*)(cb + base) = *(const uint4*)out;
}

// ---------------------------------------------------------------------------
extern "C" void kernel_launch(void* const* d_in, const int* in_sizes, int n_in,
                              void* d_out, int out_size, void* d_ws, size_t ws_size,
                              hipStream_t stream) {
    const float* Q    = (const float*)d_in[0];
    const float* K    = (const float*)d_in[1];
    const float* V    = (const float*)d_in[2];
    const void*  mask = d_in[3];
    const float* Wq   = (const float*)d_in[4];
    const float* Wo   = (const float*)d_in[5];
    float* out = (float*)d_out;

    // workspace carve (~62 MB). After proj3, Qb/Kb/Vb are dead -> overlay the
    // attention partial buffers on them (stream-ordered, re-written each call).
    const size_t NX = (size_t)MROWS * D_;
    const size_t NW = (size_t)D_ * D_;
    unsigned short* Qb   = (unsigned short*)d_ws;   // bf16 input casts
    unsigned short* Kb   = Qb + NX;
    unsigned short* Vb   = Kb + NX;
    unsigned short* Wqb  = Vb + NX;
    unsigned short* Wob  = Wqb + NW;
    unsigned short* qbuf = Wob + NW;                // q proj * 0.125*log2e (bf16)
    unsigned short* kbuf = qbuf + NX;               // k proj (bf16 RM)
    unsigned short* vtb  = kbuf + NX;               // V^T (bf16)
    unsigned short* cbuf = vtb + NX;                // context (bf16 RM)
    unsigned long long* mb = (unsigned long long*)(cbuf + NX);

    unsigned short* o0 = Qb;                        // overlay: partial O half 0
    unsigned short* o1 = Kb;                        // overlay: partial O half 1
    float* l0 = (float*)Vb;                         // overlay: partial l half 0
    float* l1 = l0 + (size_t)MROWS * H_;            // partial l half 1

    prep<<<dim3(CAST_BLOCKS + MASK_BLOCKS), dim3(256), 0, stream>>>(
        Q, K, V, Wq, Wo, mask, Qb, Kb, Vb, Wqb, Wob, mb);

    proj3<<<dim3(MROWS / 128, D_ / 128, 3), dim3(256), 0, stream>>>(
        Qb, Kb, Vb, Wqb, qbuf, kbuf, vtb);

    attn_mfma<<<dim3(S_ / 128, H_, B_ * 2), dim3(256), 0, stream>>>(
        qbuf, kbuf, vtb, mb, o0, o1, l0, l1);

    combine<<<dim3((int)(NX / 8 / 256)), dim3(256), 0, stream>>>(o0, o1, l0, l1, cbuf);

    gemm_out<<<dim3(MROWS / 128, D_ / 128), dim3(256), 0, stream>>>(cbuf, Wob, out);
}